// Round 1
// baseline (628.205 us; speedup 1.0000x reference)
//
#include <hip/hip_runtime.h>
#include <math.h>

// Fused GQA attention, MI355X/gfx950.
// B=2 S=2048 E=2048 H=16 G=4 D=128, causal, fp32 in/out, bf16 MFMA compute.
//
// Pipeline (all on `stream`):
//   1. conv_x      : x fp32 -> bf16 [4096][2048]
//   2. transpose_w : Wq/Wk/Wv [nh][E][128] fp32 -> Wt [3072][2048] bf16 (B^T layout)
//   3. build_bias  : bq|bk|bv -> bc[3072] fp32
//   4. qkv_gemm    : [4096x2048]x[2048x3072] bf16 MFMA GEMM, 128^2 tile, BK=32,
//                    global_load_lds double-buffer. Epilogue: +bias, Q pre-scaled
//                    by 1/sqrt(128), Q/K stored [bh][s][d], V stored transposed [bg][d][s].
//   5. attn        : flash attention. 4 independent waves/block, 16 q-rows/wave,
//                    KV tile = 32. Swapped QK^T (mfma(K,Q)) => per-q softmax state is
//                    lane-local (q = lane&15); P re-layout via 1KB/wave LDS; PV uses
//                    V^T so B-fragments are contiguous. K/V read direct from L2/L3.
//
// Workspace layout (bytes):  xb 0..16M | wt 16M..28M | bc 28M..+16K | qb +16M | kb +4M | vt +4M  (~52.1 MB)

typedef __attribute__((ext_vector_type(8))) short bf16x8;
typedef __attribute__((ext_vector_type(4))) short s16x4;
typedef __attribute__((ext_vector_type(4))) float f32x4;

#define LOG2E 1.4426950408889634f

__device__ __forceinline__ short f2bf(float f) {
  union { float f; unsigned u; } v; v.f = f;
  unsigned r = v.u + 0x7FFFu + ((v.u >> 16) & 1u);
  return (short)(r >> 16);
}

__device__ __forceinline__ void async16(const void* g, void* l) {
  __builtin_amdgcn_global_load_lds(
      (const __attribute__((address_space(1))) void*)g,
      (__attribute__((address_space(3))) void*)l, 16, 0, 0);
}

__device__ __forceinline__ f32x4 mfma16(bf16x8 a, bf16x8 b, f32x4 c) {
  return __builtin_amdgcn_mfma_f32_16x16x32_bf16(a, b, c, 0, 0, 0);
}

// ---------------------------------------------------------------- prep kernels

__global__ void conv_x(const float4* __restrict__ x, s16x4* __restrict__ xb) {
  const int i = blockIdx.x * 256 + threadIdx.x;  // 2,097,152 threads, 4 elems each
  float4 v = x[i];
  s16x4 o;
  o[0] = f2bf(v.x); o[1] = f2bf(v.y); o[2] = f2bf(v.z); o[3] = f2bf(v.w);
  xb[i] = o;
}

// src [nh][2048][128] fp32 -> wt rows (c0 + h*128 + d), cols e (bf16), LDS-tiled transpose
__global__ void transpose_w(const float* __restrict__ src, short* __restrict__ wt, int c0) {
  __shared__ float t[32][33];
  const int hh = blockIdx.z;
  const int e0 = blockIdx.x * 32, d0 = blockIdx.y * 32;
  const int tx = threadIdx.x, ty = threadIdx.y;  // (32, 8)
  const float* s = src + (size_t)hh * 2048 * 128;
#pragma unroll
  for (int i = ty; i < 32; i += 8)
    t[i][tx] = s[(size_t)(e0 + i) * 128 + d0 + tx];
  __syncthreads();
#pragma unroll
  for (int i = ty; i < 32; i += 8)
    wt[(size_t)(c0 + hh * 128 + d0 + i) * 2048 + e0 + tx] = f2bf(t[tx][i]);
}

__global__ void build_bias(const float* __restrict__ bq, const float* __restrict__ bk,
                           const float* __restrict__ bv, float* __restrict__ bc) {
  const int c = blockIdx.x * 256 + threadIdx.x;  // 3072 threads
  float v;
  if (c < 2048)      v = bq[c];
  else if (c < 2560) v = bk[c - 2048];
  else               v = bv[c - 2560];
  bc[c] = v;
}

// ---------------------------------------------------------------- QKV GEMM

__global__ __launch_bounds__(256) void qkv_gemm(
    const short* __restrict__ xb,   // [4096][2048] bf16
    const short* __restrict__ wt,   // [3072][2048] bf16 (B^T)
    const float* __restrict__ bc,   // [3072]
    short* __restrict__ qb,         // [B*H][S][128]  (pre-scaled by 1/sqrt(D))
    short* __restrict__ kb,         // [B*G][S][128]
    short* __restrict__ vt)         // [B*G][128][S]  (V transposed)
{
  constexpr int E = 2048, BK = 32;
  __shared__ short Al[2][128 * BK];
  __shared__ short Bl[2][128 * BK];
  const int tid = threadIdx.x;
  const int lane = tid & 63, wave = tid >> 6;
  const int wr = wave >> 1, wc = wave & 1;
  const int l16 = lane & 15, grp = lane >> 4;
  const int m0 = blockIdx.y * 128, n0 = blockIdx.x * 128;

  // staging: 512 chunks of 16B per tile; thread t handles chunks t and t+256
  const int c1 = tid, c2 = tid + 256;
  const int r1 = c1 >> 2, s1 = c1 & 3, r2 = c2 >> 2, s2 = c2 & 3;

  f32x4 acc[4][4] = {};

  async16(xb + (size_t)(m0 + r1) * E + s1 * 8, (char*)Al[0] + c1 * 16);
  async16(xb + (size_t)(m0 + r2) * E + s2 * 8, (char*)Al[0] + c2 * 16);
  async16(wt + (size_t)(n0 + r1) * E + s1 * 8, (char*)Bl[0] + c1 * 16);
  async16(wt + (size_t)(n0 + r2) * E + s2 * 8, (char*)Bl[0] + c2 * 16);
  __syncthreads();

  const int nk = E / BK;  // 64
  for (int t = 0; t < nk; ++t) {
    const int cur = t & 1;
    if (t + 1 < nk) {
      const int k0 = (t + 1) * BK;
      async16(xb + (size_t)(m0 + r1) * E + k0 + s1 * 8, (char*)Al[cur ^ 1] + c1 * 16);
      async16(xb + (size_t)(m0 + r2) * E + k0 + s2 * 8, (char*)Al[cur ^ 1] + c2 * 16);
      async16(wt + (size_t)(n0 + r1) * E + k0 + s1 * 8, (char*)Bl[cur ^ 1] + c1 * 16);
      async16(wt + (size_t)(n0 + r2) * E + k0 + s2 * 8, (char*)Bl[cur ^ 1] + c2 * 16);
    }
    bf16x8 af[4], bfr[4];
#pragma unroll
    for (int mi = 0; mi < 4; ++mi)
      af[mi] = *(const bf16x8*)&Al[cur][(wr * 64 + mi * 16 + l16) * BK + grp * 8];
#pragma unroll
    for (int ni = 0; ni < 4; ++ni)
      bfr[ni] = *(const bf16x8*)&Bl[cur][(wc * 64 + ni * 16 + l16) * BK + grp * 8];
#pragma unroll
    for (int mi = 0; mi < 4; ++mi)
#pragma unroll
      for (int ni = 0; ni < 4; ++ni)
        acc[mi][ni] = mfma16(af[mi], bfr[ni], acc[mi][ni]);
    __syncthreads();  // barrier drains vmcnt: stage(t+1) complete, reads of cur done
  }

  // epilogue: D layout col = lane&15, row = (lane>>4)*4 + reg
  const float qscale = 0.08838834764831845f;  // 1/sqrt(128)
#pragma unroll
  for (int ni = 0; ni < 4; ++ni) {
    const int c = n0 + wc * 64 + ni * 16 + l16;
    const float bias = bc[c];
    const int d = c & 127;
#pragma unroll
    for (int mi = 0; mi < 4; ++mi) {
      const int rbase = m0 + wr * 64 + mi * 16 + grp * 4;
      const int b = rbase >> 11;
      const int s = rbase & 2047;
      f32x4 a = acc[mi][ni];
      if (c < 2048) {               // Q, fold 1/sqrt(D)
        const int h = c >> 7;
        short* dst = qb + ((size_t)(b * 16 + h) * 2048 + s) * 128 + d;
#pragma unroll
        for (int r = 0; r < 4; ++r) dst[(size_t)r * 128] = f2bf((a[r] + bias) * qscale);
      } else if (c < 2560) {        // K
        const int gi = (c >> 7) & 3;
        short* dst = kb + ((size_t)(b * 4 + gi) * 2048 + s) * 128 + d;
#pragma unroll
        for (int r = 0; r < 4; ++r) dst[(size_t)r * 128] = f2bf(a[r] + bias);
      } else {                      // V -> transposed store, 4 consecutive s pack to 8B
        const int gi = (c >> 7) & 3;
        s16x4 pk;
#pragma unroll
        for (int r = 0; r < 4; ++r) pk[r] = f2bf(a[r] + bias);
        *(s16x4*)&vt[((size_t)(b * 4 + gi) * 128 + d) * 2048 + s] = pk;
      }
    }
  }
}

// ---------------------------------------------------------------- attention

__global__ __launch_bounds__(256) void attn(
    const short* __restrict__ qb, const short* __restrict__ kb,
    const short* __restrict__ vt, float* __restrict__ out)
{
  constexpr int S = 2048, D = 128;
  __shared__ short Plds[4][16][32];  // per-wave P buffer (1KB each)
  const int tid = threadIdx.x;
  const int lane = tid & 63, wave = tid >> 6;
  const int l16 = lane & 15, grp = lane >> 4;
  const int qt = blockIdx.x, h = blockIdx.y, b = blockIdx.z;
  const int g = h >> 2;                    // per = H/G = 4
  const int q0 = qt * 64 + wave * 16;      // this wave's 16 q-rows

  const short* Q = qb + (size_t)(b * 16 + h) * S * D;
  const short* K = kb + (size_t)(b * 4 + g) * S * D;
  const short* V = vt + (size_t)(b * 4 + g) * D * S;

  // hoist Q fragments (Q pre-scaled by 1/sqrt(D)); acts as B^T operand of mfma(K,Q)
  bf16x8 qf[4];
#pragma unroll
  for (int c = 0; c < 4; ++c)
    qf[c] = *(const bf16x8*)&Q[(size_t)(q0 + l16) * D + c * 32 + grp * 8];

  f32x4 o[8] = {};                 // O^T accum: col=lane&15=q, row=d_local
  float mrun = -INFINITY, lrun = 0.f;
  short (*pl)[32] = Plds[wave];
  const int kv_end = q0 + 16;

  for (int kv0 = 0; kv0 < kv_end; kv0 += 32) {
    // ST = K_tile * Q^T : ST[k_local][q], col=lane&15=q, row=grp*4+reg=k_local
    f32x4 st[2] = {};
#pragma unroll
    for (int f = 0; f < 2; ++f)
#pragma unroll
      for (int c = 0; c < 4; ++c) {
        bf16x8 kf = *(const bf16x8*)&K[(size_t)(kv0 + f * 16 + l16) * D + c * 32 + grp * 8];
        st[f] = mfma16(kf, qf[c], st[f]);
      }
    if (kv0 + 31 > q0) {           // diagonal tile: causal mask
      const int qa = q0 + l16;
#pragma unroll
      for (int f = 0; f < 2; ++f)
#pragma unroll
        for (int r = 0; r < 4; ++r)
          if (kv0 + f * 16 + grp * 4 + r > qa) st[f][r] = -INFINITY;
    }
    // per-q row max: 8 lane-local + reduce over the 4 k-groups (lanes ^16, ^32)
    float tmax = -INFINITY;
#pragma unroll
    for (int f = 0; f < 2; ++f)
#pragma unroll
      for (int r = 0; r < 4; ++r) tmax = fmaxf(tmax, st[f][r]);
    tmax = fmaxf(tmax, __shfl_xor(tmax, 16));
    tmax = fmaxf(tmax, __shfl_xor(tmax, 32));
    const float mn = fmaxf(mrun, tmax);
    const float fac = exp2f((mrun - mn) * LOG2E);
    float lsum = 0.f;
    float ps[8];
#pragma unroll
    for (int f = 0; f < 2; ++f)
#pragma unroll
      for (int r = 0; r < 4; ++r) {
        const float p = exp2f((st[f][r] - mn) * LOG2E);
        ps[f * 4 + r] = p;
        lsum += p;
      }
    lsum += __shfl_xor(lsum, 16);
    lsum += __shfl_xor(lsum, 32);
    lrun = lrun * fac + lsum;
    mrun = mn;
#pragma unroll
    for (int f8 = 0; f8 < 8; ++f8) o[f8] *= fac;

    // P -> LDS as [q][k] bf16 (2x ds_write_b64/lane), read back as B-frag (1x b128)
#pragma unroll
    for (int f = 0; f < 2; ++f) {
      s16x4 pk;
#pragma unroll
      for (int r = 0; r < 4; ++r) pk[r] = f2bf(ps[f * 4 + r]);
      *(s16x4*)&pl[l16][f * 16 + grp * 4] = pk;
    }
    const bf16x8 pb = *(const bf16x8*)&pl[l16][grp * 8];

    // O^T += V^T_tile * P : A-frag rows = d (lane&15), k contiguous from vt[d][s]
#pragma unroll
    for (int f8 = 0; f8 < 8; ++f8) {
      bf16x8 vf = *(const bf16x8*)&V[(size_t)(f8 * 16 + l16) * S + kv0 + grp * 8];
      o[f8] = mfma16(vf, pb, o[f8]);
    }
  }

  const float inv = 1.f / lrun;
  float* orow = out + ((size_t)b * S + q0 + l16) * 2048 + h * D;
#pragma unroll
  for (int f8 = 0; f8 < 8; ++f8) {
    f32x4 v = o[f8] * inv;
    *(f32x4*)&orow[f8 * 16 + grp * 4] = v;  // 16B store, 4 consecutive d
  }
}

// ---------------------------------------------------------------- launch

extern "C" void kernel_launch(void* const* d_in, const int* in_sizes, int n_in,
                              void* d_out, int out_size, void* d_ws, size_t ws_size,
                              hipStream_t stream) {
  const float* x  = (const float*)d_in[0];
  const float* Wq = (const float*)d_in[1];
  const float* bq = (const float*)d_in[2];
  const float* Wk = (const float*)d_in[3];
  const float* bk = (const float*)d_in[4];
  const float* Wv = (const float*)d_in[5];
  const float* bv = (const float*)d_in[6];
  float* out = (float*)d_out;

  char* ws = (char*)d_ws;
  short* xb = (short*)ws;                                         // 16 MB
  short* wt = (short*)(ws + (size_t)16 * 1024 * 1024);            // 12 MB
  float* bc = (float*)(ws + (size_t)28 * 1024 * 1024);            // 16 KB slot
  short* qb = (short*)(ws + (size_t)28 * 1024 * 1024 + 65536);    // 16 MB
  short* kb = (short*)((char*)qb + (size_t)16 * 1024 * 1024);     // 4 MB
  short* vt = (short*)((char*)kb + (size_t)4 * 1024 * 1024);      // 4 MB

  conv_x<<<8192, 256, 0, stream>>>((const float4*)x, (s16x4*)xb);
  dim3 tb(32, 8);
  transpose_w<<<dim3(64, 4, 16), tb, 0, stream>>>(Wq, wt, 0);
  transpose_w<<<dim3(64, 4, 4),  tb, 0, stream>>>(Wk, wt, 2048);
  transpose_w<<<dim3(64, 4, 4),  tb, 0, stream>>>(Wv, wt, 2560);
  build_bias<<<12, 256, 0, stream>>>(bq, bk, bv, bc);
  qkv_gemm<<<dim3(24, 32), 256, 0, stream>>>(xb, wt, bc, qb, kb, vt);
  attn<<<dim3(32, 16, 2), 256, 0, stream>>>(qb, kb, vt, out);
}

// Round 2
// 261.203 us; speedup vs baseline: 2.4050x; 2.4050x over previous
//
#include <hip/hip_runtime.h>
#include <math.h>

// Fused GQA attention, MI355X/gfx950.
// B=2 S=2048 E=2048 H=16 G=4 D=128, causal, fp32 in/out, bf16 MFMA compute.
//
//   1. conv_x      : x fp32 -> bf16 [4096][2048]
//   2. transpose_w : Wq/Wk/Wv [nh][E][128] fp32 -> Wt [3072][2048] bf16 (B^T layout)
//   3. build_bias  : bq|bk|bv -> bc[3072] fp32
//   4. qkv_gemm    : [4096x2048]x[2048x3072] bf16 MFMA GEMM (128^2 tile, BK=32,
//                    global_load_lds dbuf). Epilogue: +bias, Q pre-scaled 1/sqrt(D),
//                    Q/K stored [bh][s][128], V stored transposed [bg][128][s].
//   5. attn (v2)   : flash attention, GEMM-shaped schedule:
//                    256 blocks x 8 waves; block j handles q-blocks {j, 15-j}
//                    sequentially (pairing => every block = 34 KV iterations).
//                    KVBLK=64. K and V^T tiles cooperatively staged to LDS via
//                    global_load_lds (16B), double-buffered, XOR-swizzled
//                    (byte ^= (row&7)<<4) through pre-swizzled GLOBAL source
//                    addresses (LDS dest stays linear). Swapped QK^T (mfma(K,Q))
//                    keeps softmax 16-vals lane-local + 2 shfl; P roundtrip via
//                    swizzled per-wave LDS tile. LDS 80KB dynamic.

typedef __attribute__((ext_vector_type(8))) short bf16x8;
typedef __attribute__((ext_vector_type(4))) short s16x4;
typedef __attribute__((ext_vector_type(4))) float f32x4;

#define LOG2E 1.4426950408889634f

__device__ __forceinline__ short f2bf(float f) {
  union { float f; unsigned u; } v; v.f = f;
  unsigned r = v.u + 0x7FFFu + ((v.u >> 16) & 1u);
  return (short)(r >> 16);
}

__device__ __forceinline__ void async16(const void* g, void* l) {
  __builtin_amdgcn_global_load_lds(
      (const __attribute__((address_space(1))) void*)g,
      (__attribute__((address_space(3))) void*)l, 16, 0, 0);
}

__device__ __forceinline__ f32x4 mfma16(bf16x8 a, bf16x8 b, f32x4 c) {
  return __builtin_amdgcn_mfma_f32_16x16x32_bf16(a, b, c, 0, 0, 0);
}

// ---------------------------------------------------------------- prep kernels

__global__ void conv_x(const float4* __restrict__ x, s16x4* __restrict__ xb) {
  const int i = blockIdx.x * 256 + threadIdx.x;
  float4 v = x[i];
  s16x4 o;
  o[0] = f2bf(v.x); o[1] = f2bf(v.y); o[2] = f2bf(v.z); o[3] = f2bf(v.w);
  xb[i] = o;
}

__global__ void transpose_w(const float* __restrict__ src, short* __restrict__ wt, int c0) {
  __shared__ float t[32][33];
  const int hh = blockIdx.z;
  const int e0 = blockIdx.x * 32, d0 = blockIdx.y * 32;
  const int tx = threadIdx.x, ty = threadIdx.y;  // (32, 8)
  const float* s = src + (size_t)hh * 2048 * 128;
#pragma unroll
  for (int i = ty; i < 32; i += 8)
    t[i][tx] = s[(size_t)(e0 + i) * 128 + d0 + tx];
  __syncthreads();
#pragma unroll
  for (int i = ty; i < 32; i += 8)
    wt[(size_t)(c0 + hh * 128 + d0 + i) * 2048 + e0 + tx] = f2bf(t[tx][i]);
}

__global__ void build_bias(const float* __restrict__ bq, const float* __restrict__ bk,
                           const float* __restrict__ bv, float* __restrict__ bc) {
  const int c = blockIdx.x * 256 + threadIdx.x;
  float v;
  if (c < 2048)      v = bq[c];
  else if (c < 2560) v = bk[c - 2048];
  else               v = bv[c - 2560];
  bc[c] = v;
}

// ---------------------------------------------------------------- QKV GEMM

__global__ __launch_bounds__(256) void qkv_gemm(
    const short* __restrict__ xb, const short* __restrict__ wt,
    const float* __restrict__ bc,
    short* __restrict__ qb, short* __restrict__ kb, short* __restrict__ vt)
{
  constexpr int E = 2048, BK = 32;
  __shared__ short Al[2][128 * BK];
  __shared__ short Bl[2][128 * BK];
  const int tid = threadIdx.x;
  const int lane = tid & 63, wave = tid >> 6;
  const int wr = wave >> 1, wc = wave & 1;
  const int l16 = lane & 15, grp = lane >> 4;
  const int m0 = blockIdx.y * 128, n0 = blockIdx.x * 128;

  const int c1 = tid, c2 = tid + 256;
  const int r1 = c1 >> 2, s1 = c1 & 3, r2 = c2 >> 2, s2 = c2 & 3;

  f32x4 acc[4][4] = {};

  async16(xb + (size_t)(m0 + r1) * E + s1 * 8, (char*)Al[0] + c1 * 16);
  async16(xb + (size_t)(m0 + r2) * E + s2 * 8, (char*)Al[0] + c2 * 16);
  async16(wt + (size_t)(n0 + r1) * E + s1 * 8, (char*)Bl[0] + c1 * 16);
  async16(wt + (size_t)(n0 + r2) * E + s2 * 8, (char*)Bl[0] + c2 * 16);
  __syncthreads();

  const int nk = E / BK;  // 64
  for (int t = 0; t < nk; ++t) {
    const int cur = t & 1;
    if (t + 1 < nk) {
      const int k0 = (t + 1) * BK;
      async16(xb + (size_t)(m0 + r1) * E + k0 + s1 * 8, (char*)Al[cur ^ 1] + c1 * 16);
      async16(xb + (size_t)(m0 + r2) * E + k0 + s2 * 8, (char*)Al[cur ^ 1] + c2 * 16);
      async16(wt + (size_t)(n0 + r1) * E + k0 + s1 * 8, (char*)Bl[cur ^ 1] + c1 * 16);
      async16(wt + (size_t)(n0 + r2) * E + k0 + s2 * 8, (char*)Bl[cur ^ 1] + c2 * 16);
    }
    bf16x8 af[4], bfr[4];
#pragma unroll
    for (int mi = 0; mi < 4; ++mi)
      af[mi] = *(const bf16x8*)&Al[cur][(wr * 64 + mi * 16 + l16) * BK + grp * 8];
#pragma unroll
    for (int ni = 0; ni < 4; ++ni)
      bfr[ni] = *(const bf16x8*)&Bl[cur][(wc * 64 + ni * 16 + l16) * BK + grp * 8];
#pragma unroll
    for (int mi = 0; mi < 4; ++mi)
#pragma unroll
      for (int ni = 0; ni < 4; ++ni)
        acc[mi][ni] = mfma16(af[mi], bfr[ni], acc[mi][ni]);
    __syncthreads();
  }

  const float qscale = 0.08838834764831845f;  // 1/sqrt(128)
#pragma unroll
  for (int ni = 0; ni < 4; ++ni) {
    const int c = n0 + wc * 64 + ni * 16 + l16;
    const float bias = bc[c];
    const int d = c & 127;
#pragma unroll
    for (int mi = 0; mi < 4; ++mi) {
      const int rbase = m0 + wr * 64 + mi * 16 + grp * 4;
      const int b = rbase >> 11;
      const int s = rbase & 2047;
      f32x4 a = acc[mi][ni];
      if (c < 2048) {
        const int h = c >> 7;
        short* dst = qb + ((size_t)(b * 16 + h) * 2048 + s) * 128 + d;
#pragma unroll
        for (int r = 0; r < 4; ++r) dst[(size_t)r * 128] = f2bf((a[r] + bias) * qscale);
      } else if (c < 2560) {
        const int gi = (c >> 7) & 3;
        short* dst = kb + ((size_t)(b * 4 + gi) * 2048 + s) * 128 + d;
#pragma unroll
        for (int r = 0; r < 4; ++r) dst[(size_t)r * 128] = f2bf(a[r] + bias);
      } else {
        const int gi = (c >> 7) & 3;
        s16x4 pk;
#pragma unroll
        for (int r = 0; r < 4; ++r) pk[r] = f2bf(a[r] + bias);
        *(s16x4*)&vt[((size_t)(b * 4 + gi) * 128 + d) * 2048 + s] = pk;
      }
    }
  }
}

// ---------------------------------------------------------------- attention v2

// Stage K tile [64][128]bf16 (256B rows) and V^T tile [128][64]bf16 (128B rows)
// into LDS, XOR-swizzled via pre-swizzled global source (LDS dest linear).
__device__ __forceinline__ void stageKV(char* kd, char* vd,
                                        const short* __restrict__ Kg,
                                        const short* __restrict__ Vg,
                                        int kv0, int tid) {
#pragma unroll
  for (int rd = 0; rd < 2; ++rd) {
    const int off = rd * 8192 + tid * 16;
    const int row = off >> 8, colb = off & 255;
    const int sc = colb ^ ((row & 7) << 4);
    async16(Kg + (size_t)(kv0 + row) * 128 + (sc >> 1), kd + off);
  }
#pragma unroll
  for (int rd = 0; rd < 2; ++rd) {
    const int off = rd * 8192 + tid * 16;
    const int row = off >> 7, colb = off & 127;
    const int sc = colb ^ ((row & 7) << 4);
    async16(Vg + (size_t)row * 2048 + kv0 + (sc >> 1), vd + off);
  }
}

__global__ __launch_bounds__(512) void attn(
    const short* __restrict__ qb, const short* __restrict__ kb,
    const short* __restrict__ vt, float* __restrict__ out)
{
  constexpr int S = 2048, D = 128;
  extern __shared__ char lds[];
  char* const Kbuf0 = lds;
  char* const Kbuf1 = lds + 16384;
  char* const Vbuf0 = lds + 32768;
  char* const Vbuf1 = lds + 49152;
  const int tid = threadIdx.x;
  const int lane = tid & 63, wave = tid >> 6;
  const int l16 = lane & 15, grp = lane >> 4;
  const int h = blockIdx.y, b = blockIdx.z;
  const int g = h >> 2;
  const short* Qg = qb + (size_t)(b * 16 + h) * S * D;
  const short* Kg = kb + (size_t)(b * 4 + g) * S * D;
  const short* Vg = vt + (size_t)(b * 4 + g) * (size_t)D * S;
  char* const Pb = lds + 65536 + wave * 2048;  // per-wave [16][64]bf16, 128B rows
  const int swz = (l16 & 7) << 4;

#pragma unroll
  for (int p = 0; p < 2; ++p) {
    // work pairing: phase 0 -> q-block j, phase 1 -> q-block 15-j  (34 iters total)
    const int jj = p ? (15 - (int)blockIdx.x) : (int)blockIdx.x;
    const int qbase = jj * 128;
    const int q0 = qbase + wave * 16;
    const int kv_end = q0 + 16;

    bf16x8 qf[4];
#pragma unroll
    for (int c = 0; c < 4; ++c)
      qf[c] = *(const bf16x8*)&Qg[(size_t)(q0 + l16) * D + c * 32 + grp * 8];

    f32x4 o[8] = {};
    float mrun = -INFINITY, lrun = 0.f;

    const int nt = (qbase + 128) >> 6;
    stageKV(Kbuf0, Vbuf0, Kg, Vg, 0, tid);
    __syncthreads();

    for (int t = 0; t < nt; ++t) {
      const int kv0 = t << 6;
      char* const Kb = (t & 1) ? Kbuf1 : Kbuf0;
      char* const Vb = (t & 1) ? Vbuf1 : Vbuf0;
      if (t + 1 < nt)
        stageKV((t & 1) ? Kbuf0 : Kbuf1, (t & 1) ? Vbuf0 : Vbuf1, Kg, Vg, kv0 + 64, tid);

      if (kv0 < kv_end) {
        // ---- QK^T: ST[k][q], k = f*16+grp*4+r, q = l16
        f32x4 st[4] = {};
#pragma unroll
        for (int c = 0; c < 4; ++c)
#pragma unroll
          for (int f = 0; f < 4; ++f) {
            const int row = f * 16 + l16;
            bf16x8 kf = *(const bf16x8*)(Kb + row * 256 + ((c * 64 + grp * 16) ^ swz));
            st[f] = mfma16(kf, qf[c], st[f]);
          }
        if (kv0 + 63 > q0) {  // diagonal: causal mask
          const int qa = q0 + l16;
#pragma unroll
          for (int f = 0; f < 4; ++f)
#pragma unroll
            for (int r = 0; r < 4; ++r)
              if (kv0 + f * 16 + grp * 4 + r > qa) st[f][r] = -INFINITY;
        }
        // ---- online softmax (16 vals lane-local + reduce over 4 k-groups)
        float tmax = -INFINITY;
#pragma unroll
        for (int f = 0; f < 4; ++f)
#pragma unroll
          for (int r = 0; r < 4; ++r) tmax = fmaxf(tmax, st[f][r]);
        tmax = fmaxf(tmax, __shfl_xor(tmax, 16));
        tmax = fmaxf(tmax, __shfl_xor(tmax, 32));
        const float mn = fmaxf(mrun, tmax);
        const float fac = exp2f((mrun - mn) * LOG2E);
        float lsum = 0.f;
        float ps[16];
#pragma unroll
        for (int f = 0; f < 4; ++f)
#pragma unroll
          for (int r = 0; r < 4; ++r) {
            const float pv = exp2f((st[f][r] - mn) * LOG2E);
            ps[f * 4 + r] = pv;
            lsum += pv;
          }
        lsum += __shfl_xor(lsum, 16);
        lsum += __shfl_xor(lsum, 32);
        lrun = lrun * fac + lsum;
        mrun = mn;
#pragma unroll
        for (int f8 = 0; f8 < 8; ++f8) o[f8] *= fac;

        // ---- P -> per-wave swizzled LDS, read back as B-fragments
#pragma unroll
        for (int f = 0; f < 4; ++f) {
          s16x4 pk;
#pragma unroll
          for (int r = 0; r < 4; ++r) pk[r] = f2bf(ps[f * 4 + r]);
          *(s16x4*)(Pb + l16 * 128 + ((f * 32 + grp * 8) ^ swz)) = pk;
        }
        const bf16x8 pb0 = *(const bf16x8*)(Pb + l16 * 128 + ((grp * 16) ^ swz));
        const bf16x8 pb1 = *(const bf16x8*)(Pb + l16 * 128 + ((64 + grp * 16) ^ swz));

        // ---- PV: O^T[d][q] += V^T * P
#pragma unroll
        for (int f8 = 0; f8 < 8; ++f8) {
          const int row = f8 * 16 + l16;
          bf16x8 vf0 = *(const bf16x8*)(Vb + row * 128 + ((grp * 16) ^ swz));
          o[f8] = mfma16(vf0, pb0, o[f8]);
          bf16x8 vf1 = *(const bf16x8*)(Vb + row * 128 + ((64 + grp * 16) ^ swz));
          o[f8] = mfma16(vf1, pb1, o[f8]);
        }
      }
      __syncthreads();  // staging(t+1) drained + all reads of cur done
    }

    const float inv = 1.f / lrun;
    float* orow = out + ((size_t)b * S + q0 + l16) * 2048 + h * D;
#pragma unroll
    for (int f8 = 0; f8 < 8; ++f8) {
      f32x4 v = o[f8] * inv;
      *(f32x4*)&orow[f8 * 16 + grp * 4] = v;
    }
  }
}

// ---------------------------------------------------------------- launch

extern "C" void kernel_launch(void* const* d_in, const int* in_sizes, int n_in,
                              void* d_out, int out_size, void* d_ws, size_t ws_size,
                              hipStream_t stream) {
  const float* x  = (const float*)d_in[0];
  const float* Wq = (const float*)d_in[1];
  const float* bq = (const float*)d_in[2];
  const float* Wk = (const float*)d_in[3];
  const float* bk = (const float*)d_in[4];
  const float* Wv = (const float*)d_in[5];
  const float* bv = (const float*)d_in[6];
  float* out = (float*)d_out;

  char* ws = (char*)d_ws;
  short* xb = (short*)ws;                                         // 16 MB
  short* wt = (short*)(ws + (size_t)16 * 1024 * 1024);            // 12 MB
  float* bc = (float*)(ws + (size_t)28 * 1024 * 1024);            // 16 KB slot
  short* qb = (short*)(ws + (size_t)28 * 1024 * 1024 + 65536);    // 16 MB
  short* kb = (short*)((char*)qb + (size_t)16 * 1024 * 1024);     // 4 MB
  short* vt = (short*)((char*)kb + (size_t)4 * 1024 * 1024);      // 4 MB

  conv_x<<<8192, 256, 0, stream>>>((const float4*)x, (s16x4*)xb);
  dim3 tb(32, 8);
  transpose_w<<<dim3(64, 4, 16), tb, 0, stream>>>(Wq, wt, 0);
  transpose_w<<<dim3(64, 4, 4),  tb, 0, stream>>>(Wk, wt, 2048);
  transpose_w<<<dim3(64, 4, 4),  tb, 0, stream>>>(Wv, wt, 2560);
  build_bias<<<12, 256, 0, stream>>>(bq, bk, bv, bc);
  qkv_gemm<<<dim3(24, 32), 256, 0, stream>>>(xb, wt, bc, qb, kb, vt);

  hipFuncSetAttribute((const void*)attn, hipFuncAttributeMaxDynamicSharedMemorySize, 81920);
  attn<<<dim3(8, 16, 2), 512, 81920, stream>>>(qb, kb, vt, out);
}